// Round 5
// baseline (214.104 us; speedup 1.0000x reference)
//
#include <hip/hip_runtime.h>
#include <math.h>

#define NN 131072
#define KK 27
#define KP 28          // K padded to 28; slot 27 is all-zero weights / idx 0
#define FIN 3
#define FOUT 32
#define EPS 1e-5f

typedef _Float16 f16;
typedef __attribute__((ext_vector_type(8))) _Float16 f16x8;
typedef __attribute__((ext_vector_type(16))) float f32x16;

// ---------------------------------------------------------------------------
// Pack w2 -> f16 MFMA B-frags w2p[k][phase][lane][j] (phase = 16-feature
// half, zero k=27 slot) and w1 -> w1p [28][3][32] (zero k=27 row).
// B layout for v_mfma_f32_32x32x16: col = lane&31, kdim = (lane>>5)*8 + j
// ---------------------------------------------------------------------------
__global__ __launch_bounds__(256) void pack_kernel(
    const float* __restrict__ w2, const float* __restrict__ w1,
    f16* __restrict__ w2p, float* __restrict__ w1p)
{
    const int t = blockIdx.x * 256 + threadIdx.x;
    if (t < KP * 1024) {
        const int k    = t >> 10;
        const int rem  = t & 1023;
        const int half = rem >> 9;
        const int l    = (rem >> 3) & 63;
        const int j    = rem & 7;
        const int krow = half * 16 + ((l >> 5) << 3) + j;  // input-feature row
        const int n    = l & 31;                           // output column
        w2p[t] = (k < KK) ? (f16)w2[k * (FOUT * FOUT) + krow * FOUT + n]
                          : (f16)0.f;
    } else {
        const int u = t - KP * 1024;
        if (u < KP * FIN * FOUT) {
            const int k = u / (FIN * FOUT);
            w1p[u] = (k < KK) ? w1[u] : 0.f;
        }
    }
}

// ---------------------------------------------------------------------------
// Prep: LDS-tiled transpose nbr_idx [N][27] -> nbrT [28][N] (k=27 row = 0)
// so idx reads in both convs are lane-consecutive (stride-108B -> coalesced),
// plus x_feats [N,3] -> xpad [N] float4 staging. 64 nodes per block.
// ---------------------------------------------------------------------------
__global__ __launch_bounds__(256) void prep_kernel(
    const int* __restrict__ nbr_idx, const float* __restrict__ x,
    int* __restrict__ nbrT, float4* __restrict__ xpad)
{
    __shared__ int   lidx[64][29];    // padded stride vs 32 banks
    __shared__ float lx[192];
    const int t  = threadIdx.x;
    const int n0 = blockIdx.x * 64;

    const int* src = nbr_idx + (size_t)n0 * KK;   // 1728 consecutive dwords
#pragma unroll
    for (int j = 0; j < 7; ++j) {
        const int f = j * 256 + t;
        if (f < 64 * KK) lidx[f / KK][f % KK] = src[f];
    }
    if (t < 192) lx[t] = x[(size_t)n0 * 3 + t];
    __syncthreads();

    const int g = t >> 6, ln = t & 63;
#pragma unroll
    for (int j = 0; j < 7; ++j) {
        const int k = g * 7 + j;
        nbrT[(size_t)k * NN + n0 + ln] = (k < KK) ? lidx[ln][k] : 0;
    }
    if (t < 64)
        xpad[n0 + t] = make_float4(lx[t * 3], lx[t * 3 + 1], lx[t * 3 + 2], 0.f);
}

// fallback (no-transpose path): xpad staging only
__global__ __launch_bounds__(256) void pad_x_kernel(
    const float* __restrict__ x, float4* __restrict__ xp)
{
    const int n = blockIdx.x * 256 + threadIdx.x;
    if (n >= NN) return;
    const float* r = x + (size_t)n * 3;
    xp[n] = make_float4(r[0], r[1], r[2], 0.f);
}

// ---------------------------------------------------------------------------
// Phase 1: h = silu(bn1(einsum(x[nbr_idx], w1))) -> planes h0/h1 [N][16] f16
// 4-WAY K-SPLIT: block = 256 thr = 64 nodes x 4 k-groups of 7 (k=27 pad).
// 2048 blocks -> 24 waves/CU (LDS-limited): TLP hides the gather latency
// that round-3's 8-wave/CU version exposed. Groups 1-3 park partials in LDS
// (f32, [3][32][64] lane-major = conflict-free); group 0 reduces + BN/SiLU.
// ---------------------------------------------------------------------------
template<bool TR>
__global__ __launch_bounds__(256) void conv1_kernel(
    const float4* __restrict__ xpad,      // [N] padded x
    const int*    __restrict__ nbrT,      // [28][N]  (TR)
    const int*    __restrict__ nbr_idx,   // [N][27]  (!TR)
    const float*  __restrict__ w1p,       // [28][3][32] (k=27 zeros)
    const float* __restrict__ g1,  const float* __restrict__ b1,
    const float* __restrict__ m1,  const float* __restrict__ v1,
    f16* __restrict__ h0, f16* __restrict__ h1)   // [N][16] each
{
    __shared__ float racc[3][FOUT][64];   // 24 KiB
    const int t  = threadIdx.x;
    const int kg = t >> 6;                // wave-uniform k-group
    const int ln = t & 63;
    const int n  = blockIdx.x * 64 + ln;

    int idxs[7];
#pragma unroll
    for (int i = 0; i < 7; ++i) {
        const int k = kg * 7 + i;
        if (TR) idxs[i] = nbrT[(size_t)k * NN + n];          // coalesced
        else    idxs[i] = (k < KK) ? nbr_idx[(size_t)n * KK + k] : 0;
    }
#pragma unroll
    for (int i = 0; i < 7; ++i) asm volatile("" : "+v"(idxs[i]));

    float4 xs[7];
#pragma unroll
    for (int i = 0; i < 7; ++i) xs[i] = xpad[idxs[i]];       // L2-resident

    float acc[FOUT];
#pragma unroll
    for (int o = 0; o < FOUT; ++o) acc[o] = 0.f;

#pragma unroll
    for (int i = 0; i < 7; ++i) {
        const float* w = w1p + (kg * 7 + i) * (FIN * FOUT);  // uniform->s_load
#pragma unroll
        for (int o = 0; o < FOUT; ++o) {
            float a = acc[o];
            a = fmaf(xs[i].x, w[o],            a);
            a = fmaf(xs[i].y, w[FOUT + o],     a);
            a = fmaf(xs[i].z, w[2 * FOUT + o], a);
            acc[o] = a;
        }
    }

    if (kg) {                             // groups 1-3: park partials
#pragma unroll
        for (int o = 0; o < FOUT; ++o) racc[kg - 1][o][ln] = acc[o];
    }
    __syncthreads();
    if (kg) return;

#pragma unroll
    for (int o = 0; o < FOUT; ++o)
        acc[o] += racc[0][o][ln] + racc[1][o][ln] + racc[2][o][ln];

#pragma unroll
    for (int g = 0; g < 4; ++g) {
        f16x8 hv;
#pragma unroll
        for (int j = 0; j < 8; ++j) {
            const int o = g * 8 + j;
            const float sc = g1[o] * rsqrtf(v1[o] + EPS);
            float v = (acc[o] - m1[o]) * sc + b1[o];
            v = v / (1.f + __expf(-v));              // silu
            hv[j] = (f16)v;
        }
        f16* dst = (g < 2) ? (h0 + (size_t)n * 16 + (g & 1) * 8)
                           : (h1 + (size_t)n * 16 + (g & 1) * 8);
        *(f16x8*)dst = hv;
    }
}

// ---------------------------------------------------------------------------
// Phase 2 (MFMA): x_out = einsum(h[nbr_idx], w2), v_mfma_f32_32x32x16_f16.
// PLANE-SPLIT: h stored as two 4 MB planes; phase 0 sweeps all 27 k over
// plane h0 ONLY (4 MB = per-XCD-L2 resident -> gathers ~all L2 hits), then
// phase 1 over h1. Same MFMA count; partials stay in registers. Round-3
// counters (FETCH 131 MB vs 24 compulsory) showed the monolithic 8 MB h
// thrashed L2 at ~50% hit -> most gathers paid L3/HBM latency.
// Point-branch MLP+BN+ReLU fused in epilogue.
// ---------------------------------------------------------------------------
template<bool TR>
__global__ __launch_bounds__(256, 4) void conv2_mfma_kernel(
    const f16*   __restrict__ h0,        // [N][16] f16
    const f16*   __restrict__ h1,        // [N][16] f16
    const int*   __restrict__ nbrT,      // [28][N]  (TR)
    const int*   __restrict__ nbr_idx,   // [N][27]  (!TR)
    const f16*   __restrict__ w2p,       // packed [28][2][64][8] f16
    const float* __restrict__ z_feats,   // [N,3]
    const float* __restrict__ mlp_w,     // [3,32]
    const float* __restrict__ mlp_b,
    const float* __restrict__ mg, const float* __restrict__ mbe,
    const float* __restrict__ mm, const float* __restrict__ mv,
    float* __restrict__ out)             // [2,N,32]
{
    const int lane = threadIdx.x & 63;
    const int wave = threadIdx.x >> 6;
    const int base = (blockIdx.x * 4 + wave) * 32;   // this wave's node base
    const int row  = lane & 31;                      // A row
    const int hi   = lane >> 5;                      // contraction half of 8

    int idxs[KK];
#pragma unroll
    for (int k = 0; k < KK; ++k) {
        if (TR) idxs[k] = nbrT[(size_t)k * NN + base + row];  // coalesced
        else    idxs[k] = nbr_idx[(size_t)(base + row) * KK + k];
    }
#pragma unroll
    for (int k = 0; k < KK; ++k) asm volatile("" : "+v"(idxs[k]));

    f32x16 accA = {};                                // plane-0 partial
    f32x16 accB = {};                                // plane-1 partial

    const f16x8* bp = (const f16x8*)w2p;             // [k*128 + phase*64 + lane]

    // ---- phase 0: plane h0 (4 MB working set, L2-resident) ----
    {
        f16x8 a = *(const f16x8*)(h0 + (size_t)idxs[0] * 16 + hi * 8);
        f16x8 b = bp[lane];
#pragma unroll
        for (int k = 0; k < KK; ++k) {
            f16x8 na, nb2;
            const bool more = (k + 1 < KK);
            if (more) {
                na  = *(const f16x8*)(h0 + (size_t)idxs[k + 1] * 16 + hi * 8);
                nb2 = bp[(k + 1) * 128 + lane];
            }
            __builtin_amdgcn_s_setprio(1);
            accA = __builtin_amdgcn_mfma_f32_32x32x16_f16(a, b, accA, 0, 0, 0);
            __builtin_amdgcn_s_setprio(0);
            if (more) { a = na; b = nb2; }
        }
    }
    // ---- phase 1: plane h1 ----
    {
        f16x8 a = *(const f16x8*)(h1 + (size_t)idxs[0] * 16 + hi * 8);
        f16x8 b = bp[64 + lane];
#pragma unroll
        for (int k = 0; k < KK; ++k) {
            f16x8 na, nb2;
            const bool more = (k + 1 < KK);
            if (more) {
                na  = *(const f16x8*)(h1 + (size_t)idxs[k + 1] * 16 + hi * 8);
                nb2 = bp[(k + 1) * 128 + 64 + lane];
            }
            __builtin_amdgcn_s_setprio(1);
            accB = __builtin_amdgcn_mfma_f32_32x32x16_f16(a, b, accB, 0, 0, 0);
            __builtin_amdgcn_s_setprio(0);
            if (more) { a = na; b = nb2; }
        }
    }

    // ---- epilogue: point branch for output column n0, fused add + store ----
    const int n0 = lane & 31;
    const float wc0 = mlp_w[n0];
    const float wc1 = mlp_w[FOUT + n0];
    const float wc2 = mlp_w[2 * FOUT + n0];
    const float sc  = mg[n0] * rsqrtf(mv[n0] + EPS);
    const float bi  = mlp_b[n0];
    const float mmv = mm[n0];
    const float mbv = mbe[n0];

#pragma unroll
    for (int r = 0; r < 16; ++r) {
        const int m    = (r & 3) + ((r >> 2) << 3) + (hi << 2); // C/D row map
        const int node = base + m;
        const float* zr = z_feats + (size_t)node * FIN;
        float z = bi;
        z = fmaf(zr[0], wc0, z);
        z = fmaf(zr[1], wc1, z);
        z = fmaf(zr[2], wc2, z);
        z = (z - mmv) * sc + mbv;
        z = fmaxf(z, 0.f);
        const float v = accA[r] + accB[r] + z;
        out[(size_t)node * FOUT + n0] = v;
        out[(size_t)NN * FOUT + (size_t)node * FOUT + n0] = v;
    }
}

extern "C" void kernel_launch(void* const* d_in, const int* in_sizes, int n_in,
                              void* d_out, int out_size, void* d_ws, size_t ws_size,
                              hipStream_t stream) {
    const float* x_feats = (const float*)d_in[0];
    const float* z_feats = (const float*)d_in[1];
    const int*   nbr_idx = (const int*)d_in[2];
    const float* w1      = (const float*)d_in[3];
    const float* bn1_g   = (const float*)d_in[4];
    const float* bn1_b   = (const float*)d_in[5];
    const float* bn1_m   = (const float*)d_in[6];
    const float* bn1_v   = (const float*)d_in[7];
    const float* w2      = (const float*)d_in[8];
    const float* mlp_w   = (const float*)d_in[9];
    const float* mlp_b   = (const float*)d_in[10];
    const float* mlp_g   = (const float*)d_in[11];
    const float* mlp_be  = (const float*)d_in[12];
    const float* mlp_m   = (const float*)d_in[13];
    const float* mlp_v   = (const float*)d_in[14];

    // workspace layout:
    //   h0 [0,4M)  h1 [4M,8M)  w2p [8M,+56K)  w1p [8M+64K,+10.5K)
    //   xpad [9M,11M)  nbrT [11M, 11M+14.336M)   (ws >= 11M proven round 2)
    const size_t OFF_H1   = (size_t)4 * 1024 * 1024;
    const size_t OFF_W2P  = (size_t)8 * 1024 * 1024;
    const size_t OFF_W1P  = OFF_W2P + 64 * 1024;
    const size_t OFF_XPAD = (size_t)9 * 1024 * 1024;
    const size_t OFF_NBRT = (size_t)11 * 1024 * 1024;
    const size_t NBRT_SZ  = (size_t)KP * NN * 4;

    f16*    h0   = (f16*)d_ws;
    f16*    h1   = (f16*)((char*)d_ws + OFF_H1);
    f16*    w2p  = (f16*)((char*)d_ws + OFF_W2P);
    float*  w1p  = (float*)((char*)d_ws + OFF_W1P);
    float4* xpad = (float4*)((char*)d_ws + OFF_XPAD);
    int*    nbrT = (int*)((char*)d_ws + OFF_NBRT);
    const bool tr = ws_size >= OFF_NBRT + NBRT_SZ;
    float* out = (float*)d_out;

    const int pack_elems = KP * 1024 + KP * FIN * FOUT;
    pack_kernel<<<(pack_elems + 255) / 256, 256, 0, stream>>>(w2, w1, w2p, w1p);
    if (tr) {
        prep_kernel<<<NN / 64, 256, 0, stream>>>(nbr_idx, x_feats, nbrT, xpad);
        conv1_kernel<true><<<NN / 64, 256, 0, stream>>>(
            xpad, nbrT, nbr_idx, w1p, bn1_g, bn1_b, bn1_m, bn1_v, h0, h1);
        conv2_mfma_kernel<true><<<NN / 128, 256, 0, stream>>>(
            h0, h1, nbrT, nbr_idx, w2p, z_feats, mlp_w, mlp_b,
            mlp_g, mlp_be, mlp_m, mlp_v, out);
    } else {
        pad_x_kernel<<<NN / 256, 256, 0, stream>>>(x_feats, xpad);
        conv1_kernel<false><<<NN / 64, 256, 0, stream>>>(
            xpad, nbrT, nbr_idx, w1p, bn1_g, bn1_b, bn1_m, bn1_v, h0, h1);
        conv2_mfma_kernel<false><<<NN / 128, 256, 0, stream>>>(
            h0, h1, nbrT, nbr_idx, w2p, z_feats, mlp_w, mlp_b,
            mlp_g, mlp_be, mlp_m, mlp_v, out);
    }
}